// Round 3
// baseline (285.448 us; speedup 1.0000x reference)
//
#include <hip/hip_runtime.h>

// pred/target: (B=2, C=1, H=192, W=192, D=192) fp32, D contiguous.
// 5x5x5 box mean (zero pad), ncc = cross^2/(vi*vj+1e-5), loss = -mean(ncc).
//
// R9 = R8 (LDS-free separable window sums) + restored 1-deep load pipeline.
//   d-sum: in registers (each lane owns a 6-float d-window -> d-pair)
//   w-sum: DPP row_shl lane tree (8 w-rows live in 8 adjacent lanes)
//   h-sum: per-lane circular ring; SLICES % 5 == 0 + unroll-5 -> static
//          ring index, zero shift movs
// R8 post-mortem: VALUBusy 30%, occ 54%, conflicts 0, FETCH 61 MB ->
// latency-bound. Each slice's loads were consumed immediately (no
// prefetch), costing a full L2/L3 round trip per slice. R9 captures the
// current slice to locals, issues next-slice loads, then computes ->
// compiler emits counted vmcnt, latency hides under ~260 VALU cycles.

#define HH 192
#define WW 192
#define DD 192
#define BB 2
#define WWDD (WW * DD)
#define HCHUNK 41
#define NSLAB 5               // 5*41 = 205 >= 192; disjoint output slabs
#define SLICES (HCHUNK + 4)   // 45 = 9*5 -> unroll-5 folds ring rotation
#define GX 12
#define GY 12
#define GZ (BB * NSLAB)
#define NBLK (GX * GY * GZ)   // 1440, % 8 == 0 -> bijective XCD swizzle

// row_shl:n (ctrl 0x100+n): lane i reads lane i+n within its 16-lane row
// row_shr:n (ctrl 0x110+n): lane i reads lane i-n
// bound_ctrl=true: out-of-row source -> 0 (only feeds unused lanes here)
// MUST be called under full exec: a source lane with EXEC=0 also reads 0.
template <int CTRL>
__device__ __forceinline__ float dpp_f(float x) {
    union { float f; int i; } a, r;
    a.f = x;
    r.i = __builtin_amdgcn_update_dpp(0, a.i, CTRL, 0xF, 0xF, true);
    return r.f;
}

__global__ __launch_bounds__(256, 6)
void lncc_fused_kernel(const float* __restrict__ pred,
                       const float* __restrict__ targ,
                       double* __restrict__ acc_out) {
    __shared__ float wpart[4];

    // XCD-aware swizzle: dispatch-consecutive blocks round-robin XCDs, so
    // give each XCD one contiguous 180-block chunk of tile space (w/d halo
    // neighbors then share one XCD's L2).
    int flat = blockIdx.x + GX * (blockIdx.y + GY * blockIdx.z);
    flat = (flat & 7) * (NBLK / 8) + (flat >> 3);
    const int bx  = flat % GX;
    const int byz = flat / GX;
    const int by  = byz % GY;
    const int bz  = byz / GY;

    const int tid  = threadIdx.x;
    const int wid  = tid >> 6;
    const int lane = tid & 63;
    const int rj = lane & 7;   // w-row within wave (lane-fast: DPP dist 1,2,4)
    const int dx = lane >> 3;  // d-pair within wave

    const int d0 = bx * 16;
    const int w0 = by * 16;
    const int b  = bz / NSLAB;
    const int h0 = (bz - b * NSLAB) * HCHUNK;
    const int base = b * (HH * WWDD);

    // wave tile: 4 w-outputs x 16 d-outputs; rows sw = ty_base-2 .. ty_base+5
    const int ty_base = w0 + 4 * wid;
    const int sw  = ty_base - 2 + rj;
    const int sdb = d0 + 2 * dx - 2;            // 6-float window start
    const bool row_ok = ((unsigned)sw < (unsigned)WW);
    const bool ok0 = row_ok && (sdb >= 0);      // floats sdb, sdb+1
    const bool ok1 = row_ok;                    // sdb+2..3 always in-range
    const bool ok2 = row_ok && (sdb + 5 < DD);  // floats sdb+4, sdb+5
    const int  gofs = base + sw * DD + sdb;     // deref only when masked ok
    const bool hi = (rj >= 4);

    float2 P0, P1, P2, T0, T1, T2;              // in-flight (next slice)
    auto load_slice = [&](int h) {
        P0 = P1 = P2 = T0 = T1 = T2 = make_float2(0.f, 0.f);
        if ((unsigned)h < (unsigned)HH) {       // wave-uniform zero-pad guard
            const float* pp = pred + (gofs + h * WWDD);
            const float* tt = targ + (gofs + h * WWDD);
            if (ok0) { P0 = *(const float2*)pp;       T0 = *(const float2*)tt; }
            if (ok1) { P1 = *(const float2*)(pp + 2); T1 = *(const float2*)(tt + 2); }
            if (ok2) { P2 = *(const float2*)(pp + 4); T2 = *(const float2*)(tt + 4); }
        }
    };

    float ring[5][5];
#pragma unroll
    for (int q = 0; q < 5; ++q)
#pragma unroll
        for (int i = 0; i < 5; ++i) ring[q][i] = 0.f;
    float hs[5] = {0.f, 0.f, 0.f, 0.f, 0.f};
    float acc = 0.f;

    load_slice(h0 - 2);   // prefetch slice 0

#pragma unroll 1
    for (int mm = 0; mm < SLICES / 5; ++mm) {
#pragma unroll
        for (int u = 0; u < 5; ++u) {
            const int it = 5 * mm + u;

            // ---- capture current slice, then launch next (stays in flight;
            // compiler waits with counted vmcnt before the captures' use) ----
            const float p0=P0.x, p1=P0.y, p2=P1.x, p3=P1.y, p4=P2.x, p5=P2.y;
            const float q0=T0.x, q1=T0.y, q2=T1.x, q3=T1.y, q4=T2.x, q5=T2.y;
            if (it + 1 < SLICES) load_slice(h0 - 1 + it);

            // ---- d-sums for the lane's d-pair (ea = even d, eb = odd d) ----
            float ea[5], eb[5];
            ea[0] = p0+p1+p2+p3+p4;  eb[0] = ea[0]-p0+p5;
            ea[1] = q0+q1+q2+q3+q4;  eb[1] = ea[1]-q0+q5;
            const float pp0=p0*p0, pp5=p5*p5;
            const float qq0=q0*q0, qq5=q5*q5;
            const float pq0=p0*q0, pq5=p5*q5;
            ea[2] = pp0+p1*p1+p2*p2+p3*p3+p4*p4;  eb[2] = ea[2]-pp0+pp5;
            ea[3] = qq0+q1*q1+q2*q2+q3*q3+q4*q4;  eb[3] = ea[3]-qq0+qq5;
            ea[4] = pq0+p1*q1+p2*q2+p3*q3+p4*q4;  eb[4] = ea[4]-pq0+pq5;

            // ---- w-sum: rows rj..rj+4 via DPP tree; valid at rj<4.
            // Redistribute: hi lanes take the odd-d window of lane-4, so all
            // 64 lanes own exactly one output column (4 ty x 16 d per wave).
            // ALL dpp_f calls straight-line / full-exec (see dpp_f comment).
            float An[5];
#pragma unroll
            for (int q = 0; q < 5; ++q) {
                const float va = ea[q], vb = eb[q];
                float sa = va + dpp_f<0x101>(va);        // rows rj,rj+1
                sa = sa + dpp_f<0x102>(sa);              // rows rj..rj+3
                const float Wa = sa + dpp_f<0x104>(va);  // + row rj+4
                float sb = vb + dpp_f<0x101>(vb);
                sb = sb + dpp_f<0x102>(sb);
                const float Wb = sb + dpp_f<0x104>(vb);
                const float Wbs = dpp_f<0x114>(Wb);      // row_shr:4, full exec
                An[q] = hi ? Wbs : Wa;                   // v_cndmask select
            }

            // ---- h ring: static slot u (it mod 5) holds An from it-5 ----
#pragma unroll
            for (int q = 0; q < 5; ++q) {
                hs[q] += An[q] - ring[q][u];
                ring[q][u] = An[q];
            }

            if (it >= 4) {                       // wave-uniform
                const int hout = h0 + it - 4;
                if (hout < HH) {
                    const float inv = 1.0f / 125.0f;
                    const float uI = hs[0]*inv, uJ = hs[1]*inv;
                    const float I2 = hs[2]*inv, J2 = hs[3]*inv, IJ = hs[4]*inv;
                    const float cross = IJ - uI * uJ;
                    const float vi = I2 - uI * uI;
                    const float vj = J2 - uJ * uJ;
                    acc += (cross * cross) *
                           __builtin_amdgcn_rcpf(vi * vj + 1e-5f);
                }
            }
        }
    }

    // ---- block reduction, one double atomic per block ----
#pragma unroll
    for (int off = 32; off > 0; off >>= 1) acc += __shfl_down(acc, off, 64);
    if (lane == 0) wpart[wid] = acc;
    __syncthreads();
    if (tid == 0)
        atomicAdd(acc_out, (double)(wpart[0] + wpart[1] + wpart[2] + wpart[3]));
}

__global__ void lncc_finalize_kernel(const double* __restrict__ acc,
                                     float* __restrict__ out) {
    const double n = (double)BB * HH * WW * DD;
    out[0] = (float)(-acc[0] / n);
}

extern "C" void kernel_launch(void* const* d_in, const int* in_sizes, int n_in,
                              void* d_out, int out_size, void* d_ws, size_t ws_size,
                              hipStream_t stream) {
    const float* pred = (const float*)d_in[0];
    const float* targ = (const float*)d_in[1];
    float* out = (float*)d_out;
    double* acc = (double*)d_ws;

    hipMemsetAsync(d_ws, 0, sizeof(double), stream);

    dim3 grid(GX, GY, GZ);     // 12 x 12 x 10 = 1440 blocks
    dim3 block(256, 1, 1);
    lncc_fused_kernel<<<grid, block, 0, stream>>>(pred, targ, acc);
    lncc_finalize_kernel<<<1, 1, 0, stream>>>(acc, out);
}

// Round 4
// 207.363 us; speedup vs baseline: 1.3766x; 1.3766x over previous
//
#include <hip/hip_runtime.h>

// pred/target: (B=2, C=1, H=192, W=192, D=192) fp32, D contiguous.
// 5x5x5 box mean (zero pad), ncc = cross^2/(vi*vj+1e-5), loss = -mean(ncc).
//
// R10 = R6 producer/consumer LDS architecture (measured best, 88.5 us) with
// consumer 2-in-w read reuse:
//   - producer (tid<160): per-row d-sums in regs -> double-buffered LDS
//     streams (verbatim R6: measured 88.5 us component).
//   - consumer (tid<128): each thread produces TWO w-adjacent outputs,
//     reading 6 LDS rows (2ty..2ty+5) instead of 2x5: 3 reads/output vs 5.
//     Second w-sum is incremental (An_odd = An_even - row0 + row5).
//   - block = 192 threads (wave 3 of R6 deleted).
//   - HCHUNK=41/NSLAB=5 -> SLICES=45 (=0 mod 5): ring[2][5][5] fully static
//     under unroll-5 (zero shift movs); LDS buf parity is SALU (it&1)*BUFSZ.
// R6 counters said LDS-pipe bound: ~50% busy + 20% conflict cycles
// (SQ_LDS_BANK_CONFLICT 1.08e7), VALU 48%. This cuts consumer LDS read
// cycles ~40% with VALU work/output unchanged.
// (R7-R9 LDS-free DPP design abandoned: latency-anomaly at 192 us, and its
// VALU-issue floor (~58 us) is worse than this dataflow's (~43 us).)

#define HH 192
#define WW 192
#define DD 192
#define BB 2
#define WWDD (WW * DD)
#define HCHUNK 41
#define NSLAB 5               // 5*41 = 205 >= 192; disjoint output slabs
#define SLICES (HCHUNK + 4)   // 45, % 5 == 0 -> static ring index
#define GX 12
#define GY 12
#define GZ (BB * NSLAB)
#define NBLK (GX * GY * GZ)   // 1440, % 8 == 0 -> bijective XCD swizzle

// LDS stream layout (bytes), double-buffered. One slice of d-summed rows:
//   quad part (sI,sJ,sII,sJJ) : 20 rows x 17 float4 (stride 272 B)
//   IJ part                   : 20 rows x 18 floats (stride 72 B)
#define QROW 272
#define QSIZE (20 * QROW)
#define IJOFF QSIZE
#define IJROW 72
#define BUFSZ (QSIZE + 20 * IJROW)   // 6880
#define LDS_BYTES (2 * BUFSZ)        // 13760

__global__ __launch_bounds__(192, 4)
void lncc_fused_kernel(const float* __restrict__ pred,
                       const float* __restrict__ targ,
                       double* __restrict__ acc_out) {
    __shared__ alignas(16) char lds[LDS_BYTES];
    __shared__ float wpart[3];

    // XCD-aware swizzle (bijective: NBLK % 8 == 0): give each XCD a
    // contiguous chunk of tile space so w/d/h halo neighbors share one L2.
    int flat = blockIdx.x + GX * (blockIdx.y + GY * blockIdx.z);
    flat = (flat & 7) * (NBLK / 8) + (flat >> 3);
    const int bx  = flat % GX;
    const int byz = flat / GX;
    const int by  = byz % GY;
    const int bz  = byz / GY;

    const int tid = threadIdx.x;

    const int d0 = bx * 16;
    const int w0 = by * 16;
    const int b  = bz / NSLAB;
    const int h0 = (bz - b * NSLAB) * HCHUNK;
    const int base = b * (HH * WWDD);

    // ---- producer map (verbatim R6): 160 threads, one w-row x one d-pair --
    const int k  = tid >> 3;          // row 0..19  (w = w0-2+k)
    const int dx = tid & 7;           // outputs d = d0+2dx, d0+2dx+1
    const int sw  = w0 - 2 + k;
    const int sdb = d0 + 2 * dx - 2;
    const bool prod   = (tid < 160);
    const bool row_ok = prod && ((unsigned)sw < (unsigned)WW);
    const bool ok0 = row_ok && (sdb >= 0);         // floats sdb, sdb+1
    const bool ok1 = row_ok;                       // sdb+2..3 always in-range
    const bool ok2 = row_ok && (sdb + 5 < DD);     // floats sdb+4, sdb+5
    const int  gofs = base + sw * DD + sdb;        // deref only when masked ok
    char* const qW  = lds + (k * QROW + dx * 32);
    char* const ijW = lds + (IJOFF + k * IJROW + dx * 8);

    // ---- consumer map: 128 threads, tx = d-col, ty = w-pair (2 outputs) ---
    const int tx = tid & 15;
    const int ty = (tid >> 4) & 7;    // outputs w0+2ty, w0+2ty+1
    const bool cons = (tid < 128);
    const char* const qR  = lds + (2 * ty * QROW + tx * 16);
    const char* const ijR = lds + (IJOFF + 2 * ty * IJROW + tx * 4);

    // h rings (last 5 d/w-summed values) + running h-sums, for both outputs
    float ring[2][5][5];
    float hs[2][5];
#pragma unroll
    for (int w01 = 0; w01 < 2; ++w01) {
#pragma unroll
        for (int q = 0; q < 5; ++q) {
            hs[w01][q] = 0.f;
#pragma unroll
            for (int i = 0; i < 5; ++i) ring[w01][q][i] = 0.f;
        }
    }
    float acc = 0.f;

    float2 P0, P1, P2, T0, T1, T2;
    auto load_slice = [&](int h) {
        P0 = P1 = P2 = T0 = T1 = T2 = make_float2(0.f, 0.f);
        if ((unsigned)h < (unsigned)HH) {
            const float* pp = pred + (gofs + h * WWDD);
            const float* tt = targ + (gofs + h * WWDD);
            if (ok0) { P0 = *(const float2*)pp;       T0 = *(const float2*)tt; }
            if (ok1) { P1 = *(const float2*)(pp + 2); T1 = *(const float2*)(tt + 2); }
            if (ok2) { P2 = *(const float2*)(pp + 4); T2 = *(const float2*)(tt + 4); }
        }
    };

    load_slice(h0 - 2);   // prefetch slice 0

#pragma unroll 1
    for (int mm = 0; mm < SLICES / 5; ++mm) {
#pragma unroll
        for (int u = 0; u < 5; ++u) {
            const int it = 5 * mm + u;
            const int buf = (it & 1) * BUFSZ;   // SALU, wave-uniform

            // ---- produce: d-sums in registers -> stream writes ----
            if (prod) {
                const float p0 = P0.x, p1 = P0.y, p2 = P1.x, p3 = P1.y, p4 = P2.x, p5 = P2.y;
                const float q0 = T0.x, q1 = T0.y, q2 = T1.x, q3 = T1.y, q4 = T2.x, q5 = T2.y;
                const float ea0 = p0 + p1 + p2 + p3 + p4,             eb0 = ea0 - p0 + p5;
                const float ea1 = q0 + q1 + q2 + q3 + q4,             eb1 = ea1 - q0 + q5;
                const float pp0 = p0 * p0, pp5 = p5 * p5;
                const float qq0 = q0 * q0, qq5 = q5 * q5;
                const float pq0 = p0 * q0, pq5 = p5 * q5;
                const float ea2 = pp0 + p1*p1 + p2*p2 + p3*p3 + p4*p4, eb2 = ea2 - pp0 + pp5;
                const float ea3 = qq0 + q1*q1 + q2*q2 + q3*q3 + q4*q4, eb3 = ea3 - qq0 + qq5;
                const float ea4 = pq0 + p1*q1 + p2*q2 + p3*q3 + p4*q4, eb4 = ea4 - pq0 + pq5;
                *(float4*)(qW + buf)      = make_float4(ea0, ea1, ea2, ea3);
                *(float4*)(qW + buf + 16) = make_float4(eb0, eb1, eb2, eb3);
                *(float2*)(ijW + buf)     = make_float2(ea4, eb4);
            }

            // ---- prefetch next slice (in flight across the barrier) ----
            if (it + 1 < SLICES) load_slice(h0 - 1 + it);

            __syncthreads();

            // ---- consume: 6 b128 + 6 b32 reads -> TWO w-sums -> rings ----
            if (cons) {
                const char* rq = qR + buf;
                const float4 Q0 = *(const float4*)(rq);
                const float4 Q1 = *(const float4*)(rq + QROW);
                const float4 Q2 = *(const float4*)(rq + 2 * QROW);
                const float4 Q3 = *(const float4*)(rq + 3 * QROW);
                const float4 Q4 = *(const float4*)(rq + 4 * QROW);
                const float4 Q5 = *(const float4*)(rq + 5 * QROW);
                const char* ri = ijR + buf;
                const float I0 = *(const float*)(ri);
                const float I1 = *(const float*)(ri + IJROW);
                const float I2 = *(const float*)(ri + 2 * IJROW);
                const float I3 = *(const float*)(ri + 3 * IJROW);
                const float I4 = *(const float*)(ri + 4 * IJROW);
                const float I5 = *(const float*)(ri + 5 * IJROW);

                // even output (w0+2ty): rows 0..4; odd (+1): incremental
                const float Ae0 = Q0.x + Q1.x + Q2.x + Q3.x + Q4.x;
                const float Ae1 = Q0.y + Q1.y + Q2.y + Q3.y + Q4.y;
                const float Ae2 = Q0.z + Q1.z + Q2.z + Q3.z + Q4.z;
                const float Ae3 = Q0.w + Q1.w + Q2.w + Q3.w + Q4.w;
                const float Ae4 = I0 + I1 + I2 + I3 + I4;
                const float Ao0 = Ae0 - Q0.x + Q5.x;
                const float Ao1 = Ae1 - Q0.y + Q5.y;
                const float Ao2 = Ae2 - Q0.z + Q5.z;
                const float Ao3 = Ae3 - Q0.w + Q5.w;
                const float Ao4 = Ae4 - I0 + I5;

                // ring slot u (= it mod 5) holds An from it-5; all static
                hs[0][0] += Ae0 - ring[0][0][u];  ring[0][0][u] = Ae0;
                hs[0][1] += Ae1 - ring[0][1][u];  ring[0][1][u] = Ae1;
                hs[0][2] += Ae2 - ring[0][2][u];  ring[0][2][u] = Ae2;
                hs[0][3] += Ae3 - ring[0][3][u];  ring[0][3][u] = Ae3;
                hs[0][4] += Ae4 - ring[0][4][u];  ring[0][4][u] = Ae4;
                hs[1][0] += Ao0 - ring[1][0][u];  ring[1][0][u] = Ao0;
                hs[1][1] += Ao1 - ring[1][1][u];  ring[1][1][u] = Ao1;
                hs[1][2] += Ao2 - ring[1][2][u];  ring[1][2][u] = Ao2;
                hs[1][3] += Ao3 - ring[1][3][u];  ring[1][3][u] = Ao3;
                hs[1][4] += Ao4 - ring[1][4][u];  ring[1][4][u] = Ao4;

                if (it >= 4) {                    // wave-uniform
                    const int hout = h0 + it - 4;
                    if (hout < HH) {
                        const float inv = 1.0f / 125.0f;
                        {
                            const float uI = hs[0][0]*inv, uJ = hs[0][1]*inv;
                            const float i2 = hs[0][2]*inv, j2 = hs[0][3]*inv, ij = hs[0][4]*inv;
                            const float cross = ij - uI * uJ;
                            const float vi = i2 - uI * uI;
                            const float vj = j2 - uJ * uJ;
                            acc += (cross * cross) *
                                   __builtin_amdgcn_rcpf(vi * vj + 1e-5f);
                        }
                        {
                            const float uI = hs[1][0]*inv, uJ = hs[1][1]*inv;
                            const float i2 = hs[1][2]*inv, j2 = hs[1][3]*inv, ij = hs[1][4]*inv;
                            const float cross = ij - uI * uJ;
                            const float vi = i2 - uI * uI;
                            const float vj = j2 - uJ * uJ;
                            acc += (cross * cross) *
                                   __builtin_amdgcn_rcpf(vi * vj + 1e-5f);
                        }
                    }
                }
            }
            // single barrier per slice: double-buffered streams make the next
            // barrier the write/read fence for this buffer
        }
    }

    // ---- block reduction (3 waves), one double atomic per block ----
#pragma unroll
    for (int off = 32; off > 0; off >>= 1) acc += __shfl_down(acc, off, 64);
    const int wid = tid >> 6, lane = tid & 63;
    if (lane == 0) wpart[wid] = acc;
    __syncthreads();
    if (tid == 0)
        atomicAdd(acc_out, (double)(wpart[0] + wpart[1] + wpart[2]));
}

__global__ void lncc_finalize_kernel(const double* __restrict__ acc,
                                     float* __restrict__ out) {
    const double n = (double)BB * HH * WW * DD;
    out[0] = (float)(-acc[0] / n);
}

extern "C" void kernel_launch(void* const* d_in, const int* in_sizes, int n_in,
                              void* d_out, int out_size, void* d_ws, size_t ws_size,
                              hipStream_t stream) {
    const float* pred = (const float*)d_in[0];
    const float* targ = (const float*)d_in[1];
    float* out = (float*)d_out;
    double* acc = (double*)d_ws;

    hipMemsetAsync(d_ws, 0, sizeof(double), stream);

    dim3 grid(GX, GY, GZ);     // 12 x 12 x 10 = 1440 blocks
    dim3 block(192, 1, 1);     // 3 waves: producers tid<160, consumers tid<128
    lncc_fused_kernel<<<grid, block, 0, stream>>>(pred, targ, acc);
    lncc_finalize_kernel<<<1, 1, 0, stream>>>(acc, out);
}

// Round 5
// 203.065 us; speedup vs baseline: 1.4057x; 1.0212x over previous
//
#include <hip/hip_runtime.h>

// pred/target: (B=2, C=1, H=192, W=192, D=192) fp32, D contiguous.
// 5x5x5 box mean (zero pad), ncc = cross^2/(vi*vj+1e-5), loss = -mean(ncc).
//
// R11 = R6 (measured best, 88.5 us) + three individually-evidenced deltas:
//   1. static h-ring: HCHUNK=41 -> SLICES=45 (=0 mod 5), inner unroll-5,
//      ring[q][u] with compile-time u -> removes ~25 v_mov/consumer-slice
//      (R6's unroll-2 rotated the ring every slice; proven in R10).
//   2. IJROW 72->76 B (19 dwords, odd): R6's ijW b64 writes hit only even
//      banks ((18k+2dx) mod 32 always even -> 8-way on a 4-phase op);
//      odd stride mixes parity -> <=4-way.
//   3. bijective XCD swizzle (1440 % 8 == 0): measured FETCH 270->61 MB
//      across R6 (no swizzle) vs R8/R10 (swizzle).
// Everything else (producer map, consumer 16x16 all-thread map, 1 barrier
// per slice, double buffer, launch shape 256@(256,6)) is R6 verbatim.
// R10 post-mortem: halving consumers to save LDS ops collapsed occupancy
// (48->26.5%) and lengthened the per-thread chain -> 114 us. The binding
// constraint is per-slice critical path x occupancy, so keep 256 threads.

#define HH 192
#define WW 192
#define DD 192
#define BB 2
#define WWDD (WW * DD)
#define HCHUNK 41
#define NSLAB 5               // 5*41 = 205 >= 192; disjoint output slabs
#define SLICES (HCHUNK + 4)   // 45, % 5 == 0 -> static ring index
#define GX 12
#define GY 12
#define GZ (BB * NSLAB)
#define NBLK (GX * GY * GZ)   // 1440, % 8 == 0 -> bijective XCD swizzle

// LDS stream layout (bytes), double-buffered. One slice of d-summed rows:
//   quad part (sI,sJ,sII,sJJ) : 20 rows x 17 float4 (stride 272 B)
//   IJ part                   : 20 rows x 19 dwords (stride 76 B; odd-dword
//                               stride so b64 writes hit odd+even banks)
#define QROW 272
#define QSIZE (20 * QROW)
#define IJOFF QSIZE
#define IJROW 76
#define BUFSZ (QSIZE + 20 * IJROW)   // 5440 + 1520 = 6960
#define LDS_BYTES (2 * BUFSZ)        // 13920

// (256,6): 80-VGPR cap. Live state ~70 regs (ring 25 + hs 5 + prefetch 12 +
// addrs). (256,8) = 64-reg cap caused 350 MB of scratch spill traffic in R6.
__global__ __launch_bounds__(256, 6)
void lncc_fused_kernel(const float* __restrict__ pred,
                       const float* __restrict__ targ,
                       double* __restrict__ acc_out) {
    __shared__ alignas(16) char lds[LDS_BYTES];
    __shared__ float wpart[4];

    // Bijective XCD swizzle: consecutive dispatch ids round-robin the 8
    // XCDs; give each XCD one contiguous 180-block chunk so w/d/h halo
    // neighbors share one L2. (Measured: FETCH 270 MB -> 61 MB.)
    int flat = blockIdx.x + GX * (blockIdx.y + GY * blockIdx.z);
    flat = (flat & 7) * (NBLK / 8) + (flat >> 3);
    const int bx  = flat % GX;
    const int byz = flat / GX;
    const int by  = byz % GY;
    const int bz  = byz / GY;

    const int tx = threadIdx.x, ty = threadIdx.y;
    const int tid = ty * 16 + tx;

    const int d0 = bx * 16;
    const int w0 = by * 16;
    const int b  = bz / NSLAB;
    const int h0 = (bz - b * NSLAB) * HCHUNK;
    const int base = b * (HH * WWDD);

    // ---- producer map: 160 threads, one w-row (k) x one d-pair (dx) ----
    // Each loads its own 6-float window (3 x float2; neighbor overlap absorbed
    // by L1/L2), computes d-sums in registers, writes streams directly.
    const int k  = tid >> 3;          // row 0..19  (w = w0-2+k)
    const int dx = tid & 7;           // outputs d = d0+2dx, d0+2dx+1
    const int sw  = w0 - 2 + k;
    const int sdb = d0 + 2 * dx - 2;
    const bool prod   = (tid < 160);
    const bool row_ok = prod && ((unsigned)sw < (unsigned)WW);
    const bool ok0 = row_ok && (sdb >= 0);         // floats sdb, sdb+1
    const bool ok1 = row_ok;                       // sdb+2..3 always in-range
    const bool ok2 = row_ok && (sdb + 5 < DD);     // floats sdb+4, sdb+5
    const int  gofs = base + sw * DD + sdb;        // deref only when masked ok
    char* const qW  = lds + (k * QROW + dx * 32);
    char* const ijW = lds + (IJOFF + k * IJROW + dx * 8);

    // ---- consumer read bases (imm offsets cover rows and buffer parity) ----
    const char* const qR  = lds + (ty * QROW + tx * 16);
    const char* const ijR = lds + (IJOFF + ty * IJROW + tx * 4);

    // h ring (last 5 d/w-summed values) + running h-sums; slot u = it mod 5
    // is compile-time under the unroll-5 inner loop -> zero shift movs.
    float ring[5][5];
    float hs0 = 0.f, hs1 = 0.f, hs2 = 0.f, hs3 = 0.f, hs4 = 0.f;
#pragma unroll
    for (int q = 0; q < 5; ++q)
#pragma unroll
        for (int i = 0; i < 5; ++i) ring[q][i] = 0.f;
    float acc = 0.f;

    float2 P0, P1, P2, T0, T1, T2;
    auto load_slice = [&](int h) {
        P0 = P1 = P2 = T0 = T1 = T2 = make_float2(0.f, 0.f);
        if ((unsigned)h < (unsigned)HH) {
            const float* pp = pred + (gofs + h * WWDD);
            const float* tt = targ + (gofs + h * WWDD);
            if (ok0) { P0 = *(const float2*)pp;       T0 = *(const float2*)tt; }
            if (ok1) { P1 = *(const float2*)(pp + 2); T1 = *(const float2*)(tt + 2); }
            if (ok2) { P2 = *(const float2*)(pp + 4); T2 = *(const float2*)(tt + 4); }
        }
    };

    load_slice(h0 - 2);   // prefetch slice 0

#pragma unroll 1
    for (int mm = 0; mm < SLICES / 5; ++mm) {
#pragma unroll
        for (int u = 0; u < 5; ++u) {
            const int it = 5 * mm + u;
            const int buf = (it & 1) * BUFSZ;   // SALU, wave-uniform

            // ---- produce: d-sums in registers -> stream writes ----
            if (prod) {
                const float p0 = P0.x, p1 = P0.y, p2 = P1.x, p3 = P1.y, p4 = P2.x, p5 = P2.y;
                const float q0 = T0.x, q1 = T0.y, q2 = T1.x, q3 = T1.y, q4 = T2.x, q5 = T2.y;
                const float ea0 = p0 + p1 + p2 + p3 + p4,             eb0 = ea0 - p0 + p5;
                const float ea1 = q0 + q1 + q2 + q3 + q4,             eb1 = ea1 - q0 + q5;
                const float pp0 = p0 * p0, pp5 = p5 * p5;
                const float qq0 = q0 * q0, qq5 = q5 * q5;
                const float pq0 = p0 * q0, pq5 = p5 * q5;
                const float ea2 = pp0 + p1*p1 + p2*p2 + p3*p3 + p4*p4, eb2 = ea2 - pp0 + pp5;
                const float ea3 = qq0 + q1*q1 + q2*q2 + q3*q3 + q4*q4, eb3 = ea3 - qq0 + qq5;
                const float ea4 = pq0 + p1*q1 + p2*q2 + p3*q3 + p4*q4, eb4 = ea4 - pq0 + pq5;
                *(float4*)(qW + buf)      = make_float4(ea0, ea1, ea2, ea3);
                *(float4*)(qW + buf + 16) = make_float4(eb0, eb1, eb2, eb3);
                *(float2*)(ijW + buf)     = make_float2(ea4, eb4);
            }

            // ---- prefetch next slice (in flight across the barrier) ----
            if (it + 1 < SLICES) load_slice(h0 - 1 + it);

            __syncthreads();

            // ---- consume: 5 b128 + 5 b32 reads -> w-sum -> h ring -> emit ----
            const char* rq = qR + buf;
            const float4 Q0 = *(const float4*)(rq);
            const float4 Q1 = *(const float4*)(rq + QROW);
            const float4 Q2 = *(const float4*)(rq + 2 * QROW);
            const float4 Q3 = *(const float4*)(rq + 3 * QROW);
            const float4 Q4 = *(const float4*)(rq + 4 * QROW);
            const char* ri = ijR + buf;
            const float An0 = Q0.x + Q1.x + Q2.x + Q3.x + Q4.x;
            const float An1 = Q0.y + Q1.y + Q2.y + Q3.y + Q4.y;
            const float An2 = Q0.z + Q1.z + Q2.z + Q3.z + Q4.z;
            const float An3 = Q0.w + Q1.w + Q2.w + Q3.w + Q4.w;
            const float An4 = *(const float*)(ri)
                            + *(const float*)(ri + IJROW)
                            + *(const float*)(ri + 2 * IJROW)
                            + *(const float*)(ri + 3 * IJROW)
                            + *(const float*)(ri + 4 * IJROW);

            // ring slot u holds An from it-5; fully static indices
            hs0 += An0 - ring[0][u];  ring[0][u] = An0;
            hs1 += An1 - ring[1][u];  ring[1][u] = An1;
            hs2 += An2 - ring[2][u];  ring[2][u] = An2;
            hs3 += An3 - ring[3][u];  ring[3][u] = An3;
            hs4 += An4 - ring[4][u];  ring[4][u] = An4;

            if (it >= 4) {
                const int hout = h0 + it - 4;
                if (hout < HH) {
                    const float inv = 1.0f / 125.0f;
                    const float uI = hs0 * inv, uJ = hs1 * inv;
                    const float I2 = hs2 * inv, J2 = hs3 * inv, IJ = hs4 * inv;
                    const float cross = IJ - uI * uJ;
                    const float vi = I2 - uI * uI;
                    const float vj = J2 - uJ * uJ;
                    acc += (cross * cross) * __builtin_amdgcn_rcpf(vi * vj + 1e-5f);
                }
            }
            // single barrier per slice: double-buffered streams make the next
            // barrier the write/read fence for this buffer
        }
    }

    // ---- block reduction, one double atomic per block ----
#pragma unroll
    for (int off = 32; off > 0; off >>= 1) acc += __shfl_down(acc, off, 64);
    const int wid = tid >> 6, lane = tid & 63;
    if (lane == 0) wpart[wid] = acc;
    __syncthreads();
    if (tid == 0)
        atomicAdd(acc_out, (double)(wpart[0] + wpart[1] + wpart[2] + wpart[3]));
}

__global__ void lncc_finalize_kernel(const double* __restrict__ acc,
                                     float* __restrict__ out) {
    const double n = (double)BB * HH * WW * DD;
    out[0] = (float)(-acc[0] / n);
}

extern "C" void kernel_launch(void* const* d_in, const int* in_sizes, int n_in,
                              void* d_out, int out_size, void* d_ws, size_t ws_size,
                              hipStream_t stream) {
    const float* pred = (const float*)d_in[0];
    const float* targ = (const float*)d_in[1];
    float* out = (float*)d_out;
    double* acc = (double*)d_ws;

    hipMemsetAsync(d_ws, 0, sizeof(double), stream);

    dim3 grid(GX, GY, GZ);     // 12 x 12 x 10 = 1440 blocks
    dim3 block(16, 16, 1);     // 256 threads
    lncc_fused_kernel<<<grid, block, 0, stream>>>(pred, targ, acc);
    lncc_finalize_kernel<<<1, 1, 0, stream>>>(acc, out);
}

// Round 6
// 194.005 us; speedup vs baseline: 1.4713x; 1.0467x over previous
//
#include <hip/hip_runtime.h>

// pred/target: (B=2, C=1, H=192, W=192, D=192) fp32, D contiguous.
// 5x5x5 box mean (zero pad), ncc = cross^2/(vi*vj+1e-5), loss = -mean(ncc).
//
// R12 = R11 with the static h-ring made un-failable.
// R11 post-mortem: WRITE_SIZE 45 KB -> 24 MB + dur 108 us. ring[q][u] relied
// on #pragma unroll of a huge loop body; the unroll didn't materialize, u
// stayed runtime, the ring went to scratch (rule: runtime-indexed local
// arrays -> local memory), 10 scratch accesses/slice. Same signature in R9
// (13 MB). Fix: FIVE macro-expanded slice bodies with LITERAL ring slots
// (ring0[0], ring0[1], ...) on named per-channel arrays -> guaranteed SROA
// to registers regardless of unroll heuristics.
// Kept from R11 (measured): bijective XCD swizzle (FETCH 270->64 MB),
// IJROW=76 (neutral on conflicts, harmless). Producer/consumer maps,
// double buffer, 1 barrier/slice are R6-verbatim (measured best 88.5 us).

#define HH 192
#define WW 192
#define DD 192
#define BB 2
#define WWDD (WW * DD)
#define HCHUNK 41
#define NSLAB 5               // 5*41 = 205 >= 192; disjoint output slabs
#define SLICES (HCHUNK + 4)   // 45, % 5 == 0 -> literal ring slots
#define GX 12
#define GY 12
#define GZ (BB * NSLAB)
#define NBLK (GX * GY * GZ)   // 1440, % 8 == 0 -> bijective XCD swizzle

// LDS stream layout (bytes), double-buffered. One slice of d-summed rows:
//   quad part (sI,sJ,sII,sJJ) : 20 rows x 17 float4 (stride 272 B)
//   IJ part                   : 20 rows x 19 dwords (stride 76 B)
#define QROW 272
#define QSIZE (20 * QROW)
#define IJOFF QSIZE
#define IJROW 76
#define BUFSZ (QSIZE + 20 * IJROW)   // 5440 + 1520 = 6960
#define LDS_BYTES (2 * BUFSZ)        // 13920

// (256,6): 80-VGPR cap. Live state ~70 regs (ring 25 + hs 5 + prefetch 12 +
// addrs). (256,8) = 64-reg cap caused 350 MB of scratch spill traffic in R6.
__global__ __launch_bounds__(256, 6)
void lncc_fused_kernel(const float* __restrict__ pred,
                       const float* __restrict__ targ,
                       double* __restrict__ acc_out) {
    __shared__ alignas(16) char lds[LDS_BYTES];
    __shared__ float wpart[4];

    // Bijective XCD swizzle: consecutive dispatch ids round-robin the 8
    // XCDs; give each XCD one contiguous 180-block chunk so halo-sharing
    // neighbors share one L2. (Measured: FETCH 270 MB -> 64 MB.)
    int flat = blockIdx.x + GX * (blockIdx.y + GY * blockIdx.z);
    flat = (flat & 7) * (NBLK / 8) + (flat >> 3);
    const int bx  = flat % GX;
    const int byz = flat / GX;
    const int by  = byz % GY;
    const int bz  = byz / GY;

    const int tx = threadIdx.x, ty = threadIdx.y;
    const int tid = ty * 16 + tx;

    const int d0 = bx * 16;
    const int w0 = by * 16;
    const int b  = bz / NSLAB;
    const int h0 = (bz - b * NSLAB) * HCHUNK;
    const int base = b * (HH * WWDD);

    // ---- producer map: 160 threads, one w-row (k) x one d-pair (dx) ----
    const int k  = tid >> 3;          // row 0..19  (w = w0-2+k)
    const int dx = tid & 7;           // outputs d = d0+2dx, d0+2dx+1
    const int sw  = w0 - 2 + k;
    const int sdb = d0 + 2 * dx - 2;
    const bool prod   = (tid < 160);
    const bool row_ok = prod && ((unsigned)sw < (unsigned)WW);
    const bool ok0 = row_ok && (sdb >= 0);         // floats sdb, sdb+1
    const bool ok1 = row_ok;                       // sdb+2..3 always in-range
    const bool ok2 = row_ok && (sdb + 5 < DD);     // floats sdb+4, sdb+5
    const int  gofs = base + sw * DD + sdb;        // deref only when masked ok
    char* const qW  = lds + (k * QROW + dx * 32);
    char* const ijW = lds + (IJOFF + k * IJROW + dx * 8);

    // ---- consumer read bases (imm offsets cover rows and buffer parity) ----
    const char* const qR  = lds + (ty * QROW + tx * 16);
    const char* const ijR = lds + (IJOFF + ty * IJROW + tx * 4);

    // h rings: named per-channel arrays, ONLY literal indices -> registers.
    float ring0[5], ring1[5], ring2[5], ring3[5], ring4[5];
#pragma unroll
    for (int i = 0; i < 5; ++i) {
        ring0[i] = 0.f; ring1[i] = 0.f; ring2[i] = 0.f;
        ring3[i] = 0.f; ring4[i] = 0.f;
    }
    float hs0 = 0.f, hs1 = 0.f, hs2 = 0.f, hs3 = 0.f, hs4 = 0.f;
    float acc = 0.f;

    float2 P0, P1, P2, T0, T1, T2;
    auto load_slice = [&](int h) {
        P0 = P1 = P2 = T0 = T1 = T2 = make_float2(0.f, 0.f);
        if ((unsigned)h < (unsigned)HH) {
            const float* pp = pred + (gofs + h * WWDD);
            const float* tt = targ + (gofs + h * WWDD);
            if (ok0) { P0 = *(const float2*)pp;       T0 = *(const float2*)tt; }
            if (ok1) { P1 = *(const float2*)(pp + 2); T1 = *(const float2*)(tt + 2); }
            if (ok2) { P2 = *(const float2*)(pp + 4); T2 = *(const float2*)(tt + 4); }
        }
    };

    load_slice(h0 - 2);   // prefetch slice 0

#define SLICE_BODY(U)                                                         \
    {                                                                         \
        const int it = 5 * mm + (U);                                          \
        const int buf = (it & 1) * BUFSZ;                                     \
        if (prod) {                                                           \
            const float p0 = P0.x, p1 = P0.y, p2 = P1.x, p3 = P1.y,           \
                        p4 = P2.x, p5 = P2.y;                                 \
            const float q0 = T0.x, q1 = T0.y, q2 = T1.x, q3 = T1.y,           \
                        q4 = T2.x, q5 = T2.y;                                 \
            const float ea0 = p0 + p1 + p2 + p3 + p4, eb0 = ea0 - p0 + p5;    \
            const float ea1 = q0 + q1 + q2 + q3 + q4, eb1 = ea1 - q0 + q5;    \
            const float pp0 = p0 * p0, pp5 = p5 * p5;                         \
            const float qq0 = q0 * q0, qq5 = q5 * q5;                         \
            const float pq0 = p0 * q0, pq5 = p5 * q5;                         \
            const float ea2 = pp0 + p1*p1 + p2*p2 + p3*p3 + p4*p4,            \
                        eb2 = ea2 - pp0 + pp5;                                \
            const float ea3 = qq0 + q1*q1 + q2*q2 + q3*q3 + q4*q4,            \
                        eb3 = ea3 - qq0 + qq5;                                \
            const float ea4 = pq0 + p1*q1 + p2*q2 + p3*q3 + p4*q4,            \
                        eb4 = ea4 - pq0 + pq5;                                \
            *(float4*)(qW + buf)      = make_float4(ea0, ea1, ea2, ea3);      \
            *(float4*)(qW + buf + 16) = make_float4(eb0, eb1, eb2, eb3);      \
            *(float2*)(ijW + buf)     = make_float2(ea4, eb4);                \
        }                                                                     \
        if (it + 1 < SLICES) load_slice(h0 - 1 + it);                         \
        __syncthreads();                                                      \
        const char* rq = qR + buf;                                            \
        const float4 Q0 = *(const float4*)(rq);                               \
        const float4 Q1 = *(const float4*)(rq + QROW);                        \
        const float4 Q2 = *(const float4*)(rq + 2 * QROW);                    \
        const float4 Q3 = *(const float4*)(rq + 3 * QROW);                    \
        const float4 Q4 = *(const float4*)(rq + 4 * QROW);                    \
        const char* ri = ijR + buf;                                           \
        const float An0 = Q0.x + Q1.x + Q2.x + Q3.x + Q4.x;                   \
        const float An1 = Q0.y + Q1.y + Q2.y + Q3.y + Q4.y;                   \
        const float An2 = Q0.z + Q1.z + Q2.z + Q3.z + Q4.z;                   \
        const float An3 = Q0.w + Q1.w + Q2.w + Q3.w + Q4.w;                   \
        const float An4 = *(const float*)(ri)                                 \
                        + *(const float*)(ri + IJROW)                         \
                        + *(const float*)(ri + 2 * IJROW)                     \
                        + *(const float*)(ri + 3 * IJROW)                     \
                        + *(const float*)(ri + 4 * IJROW);                    \
        hs0 += An0 - ring0[(U)];  ring0[(U)] = An0;                           \
        hs1 += An1 - ring1[(U)];  ring1[(U)] = An1;                           \
        hs2 += An2 - ring2[(U)];  ring2[(U)] = An2;                           \
        hs3 += An3 - ring3[(U)];  ring3[(U)] = An3;                           \
        hs4 += An4 - ring4[(U)];  ring4[(U)] = An4;                           \
        if (it >= 4) {                                                        \
            const int hout = h0 + it - 4;                                     \
            if (hout < HH) {                                                  \
                const float inv = 1.0f / 125.0f;                              \
                const float uI = hs0 * inv, uJ = hs1 * inv;                   \
                const float I2 = hs2 * inv, J2 = hs3 * inv, IJ = hs4 * inv;   \
                const float cross = IJ - uI * uJ;                             \
                const float vi = I2 - uI * uI;                                \
                const float vj = J2 - uJ * uJ;                                \
                acc += (cross * cross) *                                      \
                       __builtin_amdgcn_rcpf(vi * vj + 1e-5f);                \
            }                                                                 \
        }                                                                     \
    }

#pragma unroll 1
    for (int mm = 0; mm < SLICES / 5; ++mm) {
        SLICE_BODY(0)
        SLICE_BODY(1)
        SLICE_BODY(2)
        SLICE_BODY(3)
        SLICE_BODY(4)
    }
#undef SLICE_BODY

    // ---- block reduction, one double atomic per block ----
#pragma unroll
    for (int off = 32; off > 0; off >>= 1) acc += __shfl_down(acc, off, 64);
    const int wid = tid >> 6, lane = tid & 63;
    if (lane == 0) wpart[wid] = acc;
    __syncthreads();
    if (tid == 0)
        atomicAdd(acc_out, (double)(wpart[0] + wpart[1] + wpart[2] + wpart[3]));
}

__global__ void lncc_finalize_kernel(const double* __restrict__ acc,
                                     float* __restrict__ out) {
    const double n = (double)BB * HH * WW * DD;
    out[0] = (float)(-acc[0] / n);
}

extern "C" void kernel_launch(void* const* d_in, const int* in_sizes, int n_in,
                              void* d_out, int out_size, void* d_ws, size_t ws_size,
                              hipStream_t stream) {
    const float* pred = (const float*)d_in[0];
    const float* targ = (const float*)d_in[1];
    float* out = (float*)d_out;
    double* acc = (double*)d_ws;

    hipMemsetAsync(d_ws, 0, sizeof(double), stream);

    dim3 grid(GX, GY, GZ);     // 12 x 12 x 10 = 1440 blocks
    dim3 block(16, 16, 1);     // 256 threads
    lncc_fused_kernel<<<grid, block, 0, stream>>>(pred, targ, acc);
    lncc_finalize_kernel<<<1, 1, 0, stream>>>(acc, out);
}

// Round 8
// 186.227 us; speedup vs baseline: 1.5328x; 1.0418x over previous
//
#include <hip/hip_runtime.h>

// pred/target: (B=2, C=1, H=192, W=192, D=192) fp32, D contiguous.
// 5x5x5 box mean (zero pad), ncc = cross^2/(vi*vj+1e-5), loss = -mean(ncc).
//
// R14 = R13 resubmitted verbatim (R13's bench died in the harness --
// "container failed twice" -- no data either way).
// R13 = R6 (measured best, 88.5 us) with ONE change: channel-planar LDS
// layout with odd dword row stride (19 dwords = 76 B).
// Evidence: R6's SQ_LDS_BANK_CONFLICT = 1.08e7 ~ 20% of wall; R11's IJROW
// 72->76 experiment moved it by only 4%, localizing conflicts to the Q
// stream whose 272 B stride (68 dwords = 4 mod 32) degenerates banks.
// float4 packing makes that unfixable (bank-quad period 8 for ANY 16B
// stride), so channels become 5 separate planes, all accesses b32/float,
// row stride 19 dwords: read-lane bank multiplicity <=2 (free), write <=3
// on 20% of traffic. Bytes and min pipe cycles unchanged; addressing is
// base + compile-time immediates (c*1520 + i*76 + buf, max 13984 < 64K).
// Everything else is R6 verbatim (R10-R12 lesson: stacked deltas on this
// kernel interact via allocator/occupancy; single-variable only).
//   - R12 showed static-ring saved no VALU (42 us total both ways) ->
//     keep R6's unroll-2 + shift ring (proven 45 KB WRITE, no scratch).
//   - swizzle deferred: FETCH 270->64 MB proven, wall-time effect not
//     isolated; candidate for next round on top of this if R13/R14 wins.

#define HH 192
#define WW 192
#define DD 192
#define BB 2
#define WWDD (WW * DD)
#define HCHUNK 40
#define NSLAB 5              // 5*40 = 200 >= 192; grid 12*12*10 = 1440 blocks
#define SLICES (HCHUNK + 4)  // 44, even -> unroll-2 folds buffer parity

// LDS: 5 channel planes (sI, sJ, sII, sJJ, sIJ), double-buffered.
// Plane row: 20 rows x 19 dwords (76 B, ODD dword stride -> banks spread).
// Row k holds d-pair outputs: dwords 2dx (ea) and 2dx+1 (eb), dx = 0..7.
#define RS 76                 // row stride bytes (19 dwords)
#define PLANE (20 * RS)       // 1520 B per channel plane
#define BUFSZ (5 * PLANE)     // 7600 B per buffer
#define LDS_BYTES (2 * BUFSZ) // 15200 B

// (256,6): 80-VGPR cap. Live state ~70 regs (ring 25 + hs 5 + prefetch 12 +
// addrs). (256,8) = 64-reg cap caused 350 MB of scratch spill traffic in R6.
__global__ __launch_bounds__(256, 6)
void lncc_fused_kernel(const float* __restrict__ pred,
                       const float* __restrict__ targ,
                       double* __restrict__ acc_out) {
    __shared__ alignas(16) char lds[LDS_BYTES];
    __shared__ float wpart[4];

    const int tx = threadIdx.x, ty = threadIdx.y;
    const int tid = ty * 16 + tx;

    const int d0 = blockIdx.x * 16;
    const int w0 = blockIdx.y * 16;
    const int bz = blockIdx.z;
    const int b  = bz / NSLAB;
    const int h0 = (bz - b * NSLAB) * HCHUNK;
    const int base = b * (HH * WWDD);

    // ---- producer map: 160 threads, one w-row (k) x one d-pair (dx) ----
    // Each loads its own 6-float window (3 x float2; neighbor overlap absorbed
    // by L1/L2), computes d-sums in registers, writes streams directly.
    const int k  = tid >> 3;          // row 0..19  (w = w0-2+k)
    const int dx = tid & 7;           // outputs d = d0+2dx, d0+2dx+1
    const int sw  = w0 - 2 + k;
    const int sdb = d0 + 2 * dx - 2;
    const bool prod   = (tid < 160);
    const bool row_ok = prod && ((unsigned)sw < (unsigned)WW);
    const bool ok0 = row_ok && (sdb >= 0);         // floats sdb, sdb+1
    const bool ok1 = row_ok;                       // sdb+2..3 always in-range
    const bool ok2 = row_ok && (sdb + 5 < DD);     // floats sdb+4, sdb+5
    const int  gofs = base + sw * DD + sdb;        // deref only when masked ok
    char* const sW = lds + (k * RS + dx * 8);      // + buf + c*PLANE (+4 for eb)

    // ---- consumer read base (imm offsets cover channel, row, parity) ----
    const char* const sR = lds + (ty * RS + tx * 4);

    // h ring (last 5 d/w-summed values) + running h-sums
    float ring[5][5];
    float hs0 = 0.f, hs1 = 0.f, hs2 = 0.f, hs3 = 0.f, hs4 = 0.f;
#pragma unroll
    for (int q = 0; q < 5; ++q)
#pragma unroll
        for (int i = 0; i < 5; ++i) ring[q][i] = 0.f;
    float acc = 0.f;

    float2 P0, P1, P2, T0, T1, T2;
    auto load_slice = [&](int h) {
        P0 = P1 = P2 = T0 = T1 = T2 = make_float2(0.f, 0.f);
        if ((unsigned)h < (unsigned)HH) {
            const float* pp = pred + (gofs + h * WWDD);
            const float* tt = targ + (gofs + h * WWDD);
            if (ok0) { P0 = *(const float2*)pp;       T0 = *(const float2*)tt; }
            if (ok1) { P1 = *(const float2*)(pp + 2); T1 = *(const float2*)(tt + 2); }
            if (ok2) { P2 = *(const float2*)(pp + 4); T2 = *(const float2*)(tt + 4); }
        }
    };

    load_slice(h0 - 2);   // prefetch slice 0

#pragma unroll 2
    for (int it = 0; it < SLICES; ++it) {
        const int buf = (it & 1) * BUFSZ;

        // ---- produce: d-sums in registers -> per-channel b32 writes ----
        if (prod) {
            const float p0 = P0.x, p1 = P0.y, p2 = P1.x, p3 = P1.y, p4 = P2.x, p5 = P2.y;
            const float q0 = T0.x, q1 = T0.y, q2 = T1.x, q3 = T1.y, q4 = T2.x, q5 = T2.y;
            const float ea0 = p0 + p1 + p2 + p3 + p4,             eb0 = ea0 - p0 + p5;
            const float ea1 = q0 + q1 + q2 + q3 + q4,             eb1 = ea1 - q0 + q5;
            const float pp0 = p0 * p0, pp5 = p5 * p5;
            const float qq0 = q0 * q0, qq5 = q5 * q5;
            const float pq0 = p0 * q0, pq5 = p5 * q5;
            const float ea2 = pp0 + p1*p1 + p2*p2 + p3*p3 + p4*p4, eb2 = ea2 - pp0 + pp5;
            const float ea3 = qq0 + q1*q1 + q2*q2 + q3*q3 + q4*q4, eb3 = ea3 - qq0 + qq5;
            const float ea4 = pq0 + p1*q1 + p2*q2 + p3*q3 + p4*q4, eb4 = ea4 - pq0 + pq5;
            char* const w = sW + buf;
            *(float*)(w)                 = ea0;
            *(float*)(w + 4)             = eb0;
            *(float*)(w + PLANE)         = ea1;
            *(float*)(w + PLANE + 4)     = eb1;
            *(float*)(w + 2 * PLANE)     = ea2;
            *(float*)(w + 2 * PLANE + 4) = eb2;
            *(float*)(w + 3 * PLANE)     = ea3;
            *(float*)(w + 3 * PLANE + 4) = eb3;
            *(float*)(w + 4 * PLANE)     = ea4;
            *(float*)(w + 4 * PLANE + 4) = eb4;
        }

        // ---- prefetch next slice (in flight across the barrier) ----
        if (it + 1 < SLICES) load_slice(h0 - 1 + it);

        __syncthreads();

        // ---- consume: 25 b32 reads (5 channels x 5 rows), all imm offsets --
        const char* rb = sR + buf;
        const float An0 = *(const float*)(rb)
                        + *(const float*)(rb + RS)
                        + *(const float*)(rb + 2 * RS)
                        + *(const float*)(rb + 3 * RS)
                        + *(const float*)(rb + 4 * RS);
        const float An1 = *(const float*)(rb + PLANE)
                        + *(const float*)(rb + PLANE + RS)
                        + *(const float*)(rb + PLANE + 2 * RS)
                        + *(const float*)(rb + PLANE + 3 * RS)
                        + *(const float*)(rb + PLANE + 4 * RS);
        const float An2 = *(const float*)(rb + 2 * PLANE)
                        + *(const float*)(rb + 2 * PLANE + RS)
                        + *(const float*)(rb + 2 * PLANE + 2 * RS)
                        + *(const float*)(rb + 2 * PLANE + 3 * RS)
                        + *(const float*)(rb + 2 * PLANE + 4 * RS);
        const float An3 = *(const float*)(rb + 3 * PLANE)
                        + *(const float*)(rb + 3 * PLANE + RS)
                        + *(const float*)(rb + 3 * PLANE + 2 * RS)
                        + *(const float*)(rb + 3 * PLANE + 3 * RS)
                        + *(const float*)(rb + 3 * PLANE + 4 * RS);
        const float An4 = *(const float*)(rb + 4 * PLANE)
                        + *(const float*)(rb + 4 * PLANE + RS)
                        + *(const float*)(rb + 4 * PLANE + 2 * RS)
                        + *(const float*)(rb + 4 * PLANE + 3 * RS)
                        + *(const float*)(rb + 4 * PLANE + 4 * RS);

        hs0 += An0 - ring[0][0];
        hs1 += An1 - ring[1][0];
        hs2 += An2 - ring[2][0];
        hs3 += An3 - ring[3][0];
        hs4 += An4 - ring[4][0];
#pragma unroll
        for (int q = 0; q < 5; ++q)
#pragma unroll
            for (int i = 0; i < 4; ++i) ring[q][i] = ring[q][i + 1];
        ring[0][4] = An0; ring[1][4] = An1; ring[2][4] = An2;
        ring[3][4] = An3; ring[4][4] = An4;

        if (it >= 4) {
            const int hout = h0 + it - 4;
            if (hout < HH) {
                const float inv = 1.0f / 125.0f;
                const float uI = hs0 * inv, uJ = hs1 * inv;
                const float I2 = hs2 * inv, J2 = hs3 * inv, IJ = hs4 * inv;
                const float cross = IJ - uI * uJ;
                const float vi = I2 - uI * uI;
                const float vj = J2 - uJ * uJ;
                acc += (cross * cross) * __builtin_amdgcn_rcpf(vi * vj + 1e-5f);
            }
        }
        // single barrier per slice: double-buffered streams make the next
        // barrier the write/read fence for this buffer
    }

    // ---- block reduction, one double atomic per block ----
#pragma unroll
    for (int off = 32; off > 0; off >>= 1) acc += __shfl_down(acc, off, 64);
    const int wid = tid >> 6, lane = tid & 63;
    if (lane == 0) wpart[wid] = acc;
    __syncthreads();
    if (tid == 0)
        atomicAdd(acc_out, (double)(wpart[0] + wpart[1] + wpart[2] + wpart[3]));
}

__global__ void lncc_finalize_kernel(const double* __restrict__ acc,
                                     float* __restrict__ out) {
    const double n = (double)BB * HH * WW * DD;
    out[0] = (float)(-acc[0] / n);
}

extern "C" void kernel_launch(void* const* d_in, const int* in_sizes, int n_in,
                              void* d_out, int out_size, void* d_ws, size_t ws_size,
                              hipStream_t stream) {
    const float* pred = (const float*)d_in[0];
    const float* targ = (const float*)d_in[1];
    float* out = (float*)d_out;
    double* acc = (double*)d_ws;

    hipMemsetAsync(d_ws, 0, sizeof(double), stream);

    dim3 grid(DD / 16, WW / 16, BB * NSLAB);   // 12 x 12 x 10 = 1440 blocks
    dim3 block(16, 16, 1);                     // 256 threads
    lncc_fused_kernel<<<grid, block, 0, stream>>>(pred, targ, acc);
    lncc_finalize_kernel<<<1, 1, 0, stream>>>(acc, out);
}

// Round 9
// 173.023 us; speedup vs baseline: 1.6498x; 1.0763x over previous
//
#include <hip/hip_runtime.h>

// pred/target: (B=2, C=1, H=192, W=192, D=192) fp32, D contiguous.
// 5x5x5 box mean (zero pad), ncc = cross^2/(vi*vj+1e-5), loss = -mean(ncc).
//
// R15 = R6 (measured best, 88.5 us) + ONE change: bijective XCD swizzle.
// Decisive test between two hypotheses:
//  H2 (HBM-service bound): R6/R14 both sit at FETCH 270 MB, 3.05-3.09 TB/s,
//     wall = 270MB/3.07TBps = 88 us BOTH times, insensitive to +60% LDS ops
//     and +47% conflicts (R14). All swizzled variants (R8-R12) measured
//     FETCH ~62 MB (4.3x less, structure-independent). If H2: wall -> 55-72.
//  H1 (barrier/latency bound): swizzle changes nothing -> wall ~88; then the
//     wave-autonomous no-barrier design is next, with traffic penalty known
//     to be safe.
// R14 post-mortem: planar-b32 layout RAISED conflicts to 1.58e7 and LDS
// instrs +60% with wall +1% -> kernel is NOT LDS-bound; that line is dead.
// Everything below the swizzle is R6 verbatim (proven 40 VGPR, no scratch).

#define HH 192
#define WW 192
#define DD 192
#define BB 2
#define WWDD (WW * DD)
#define HCHUNK 40
#define NSLAB 5              // 5*40 = 200 >= 192; grid 12*12*10 = 1440 blocks
#define SLICES (HCHUNK + 4)  // 44, even -> unroll-2 folds buffer parity
#define GX 12
#define GY 12
#define GZ (BB * NSLAB)
#define NBLK (GX * GY * GZ)  // 1440, % 8 == 0 -> bijective XCD swizzle

// LDS stream layout (bytes), double-buffered. One slice of d-summed rows:
//   quad part (sI,sJ,sII,sJJ) : 20 rows x 17 float4 (stride 272 B)  -> 5440 B
//   IJ part                   : 20 rows x 18 floats (stride 72 B)   -> 1440 B
#define QROW 272
#define QSIZE (20 * QROW)
#define IJOFF QSIZE
#define IJROW 72
#define BUFSZ (QSIZE + 20 * IJROW)   // 6880
#define LDS_BYTES (2 * BUFSZ)        // 13760

// (256,6): 80-VGPR cap. Live state ~70 regs (ring 25 + hs 5 + prefetch 12 +
// addrs). (256,8) = 64-reg cap caused 350 MB of scratch spill traffic in R6.
__global__ __launch_bounds__(256, 6)
void lncc_fused_kernel(const float* __restrict__ pred,
                       const float* __restrict__ targ,
                       double* __restrict__ acc_out) {
    __shared__ alignas(16) char lds[LDS_BYTES];
    __shared__ float wpart[4];

    // Bijective XCD swizzle (1440 % 8 == 0): dispatch-consecutive blocks
    // round-robin the 8 XCDs; give each XCD one contiguous 180-block chunk
    // of tile space so halo-sharing neighbors hit one XCD's L2/L3 path.
    // Measured across R8-R12: FETCH_SIZE 270 MB -> ~62 MB.
    int flat = blockIdx.x + GX * (blockIdx.y + GY * blockIdx.z);
    flat = (flat & 7) * (NBLK / 8) + (flat >> 3);
    const int bx  = flat % GX;
    const int byz = flat / GX;
    const int by  = byz % GY;
    const int bz  = byz / GY;

    const int tx = threadIdx.x, ty = threadIdx.y;
    const int tid = ty * 16 + tx;

    const int d0 = bx * 16;
    const int w0 = by * 16;
    const int b  = bz / NSLAB;
    const int h0 = (bz - b * NSLAB) * HCHUNK;
    const int base = b * (HH * WWDD);

    // ---- producer map: 160 threads, one w-row (k) x one d-pair (dx) ----
    // Each loads its own 6-float window (3 x float2; neighbor overlap absorbed
    // by L1/L2), computes d-sums in registers, writes streams directly.
    const int k  = tid >> 3;          // row 0..19  (w = w0-2+k)
    const int dx = tid & 7;           // outputs d = d0+2dx, d0+2dx+1
    const int sw  = w0 - 2 + k;
    const int sdb = d0 + 2 * dx - 2;
    const bool prod   = (tid < 160);
    const bool row_ok = prod && ((unsigned)sw < (unsigned)WW);
    const bool ok0 = row_ok && (sdb >= 0);         // floats sdb, sdb+1
    const bool ok1 = row_ok;                       // sdb+2..3 always in-range
    const bool ok2 = row_ok && (sdb + 5 < DD);     // floats sdb+4, sdb+5
    const int  gofs = base + sw * DD + sdb;        // deref only when masked ok
    char* const qW  = lds + (k * QROW + dx * 32);
    char* const ijW = lds + (IJOFF + k * IJROW + dx * 8);

    // ---- consumer read bases (imm offsets cover rows and buffer parity) ----
    const char* const qR  = lds + (ty * QROW + tx * 16);
    const char* const ijR = lds + (IJOFF + ty * IJROW + tx * 4);

    // h ring (last 5 d/w-summed values) + running h-sums
    float ring[5][5];
    float hs0 = 0.f, hs1 = 0.f, hs2 = 0.f, hs3 = 0.f, hs4 = 0.f;
#pragma unroll
    for (int q = 0; q < 5; ++q)
#pragma unroll
        for (int i = 0; i < 5; ++i) ring[q][i] = 0.f;
    float acc = 0.f;

    float2 P0, P1, P2, T0, T1, T2;
    auto load_slice = [&](int h) {
        P0 = P1 = P2 = T0 = T1 = T2 = make_float2(0.f, 0.f);
        if ((unsigned)h < (unsigned)HH) {
            const float* pp = pred + (gofs + h * WWDD);
            const float* tt = targ + (gofs + h * WWDD);
            if (ok0) { P0 = *(const float2*)pp;       T0 = *(const float2*)tt; }
            if (ok1) { P1 = *(const float2*)(pp + 2); T1 = *(const float2*)(tt + 2); }
            if (ok2) { P2 = *(const float2*)(pp + 4); T2 = *(const float2*)(tt + 4); }
        }
    };

    load_slice(h0 - 2);   // prefetch slice 0

#pragma unroll 2
    for (int it = 0; it < SLICES; ++it) {
        const int buf = (it & 1) * BUFSZ;

        // ---- produce: d-sums in registers -> stream writes ----
        if (prod) {
            const float p0 = P0.x, p1 = P0.y, p2 = P1.x, p3 = P1.y, p4 = P2.x, p5 = P2.y;
            const float q0 = T0.x, q1 = T0.y, q2 = T1.x, q3 = T1.y, q4 = T2.x, q5 = T2.y;
            const float ea0 = p0 + p1 + p2 + p3 + p4,             eb0 = ea0 - p0 + p5;
            const float ea1 = q0 + q1 + q2 + q3 + q4,             eb1 = ea1 - q0 + q5;
            const float pp0 = p0 * p0, pp5 = p5 * p5;
            const float qq0 = q0 * q0, qq5 = q5 * q5;
            const float pq0 = p0 * q0, pq5 = p5 * q5;
            const float ea2 = pp0 + p1*p1 + p2*p2 + p3*p3 + p4*p4, eb2 = ea2 - pp0 + pp5;
            const float ea3 = qq0 + q1*q1 + q2*q2 + q3*q3 + q4*q4, eb3 = ea3 - qq0 + qq5;
            const float ea4 = pq0 + p1*q1 + p2*q2 + p3*q3 + p4*q4, eb4 = ea4 - pq0 + pq5;
            *(float4*)(qW + buf)      = make_float4(ea0, ea1, ea2, ea3);
            *(float4*)(qW + buf + 16) = make_float4(eb0, eb1, eb2, eb3);
            *(float2*)(ijW + buf)     = make_float2(ea4, eb4);
        }

        // ---- prefetch next slice (in flight across the barrier) ----
        if (it + 1 < SLICES) load_slice(h0 - 1 + it);

        __syncthreads();

        // ---- consume: 5 b128 + 5 b32 reads -> w-sum -> h ring -> emit ----
        const char* rq = qR + buf;
        const float4 Q0 = *(const float4*)(rq);
        const float4 Q1 = *(const float4*)(rq + QROW);
        const float4 Q2 = *(const float4*)(rq + 2 * QROW);
        const float4 Q3 = *(const float4*)(rq + 3 * QROW);
        const float4 Q4 = *(const float4*)(rq + 4 * QROW);
        const char* ri = ijR + buf;
        const float An0 = Q0.x + Q1.x + Q2.x + Q3.x + Q4.x;
        const float An1 = Q0.y + Q1.y + Q2.y + Q3.y + Q4.y;
        const float An2 = Q0.z + Q1.z + Q2.z + Q3.z + Q4.z;
        const float An3 = Q0.w + Q1.w + Q2.w + Q3.w + Q4.w;
        const float An4 = *(const float*)(ri)
                        + *(const float*)(ri + IJROW)
                        + *(const float*)(ri + 2 * IJROW)
                        + *(const float*)(ri + 3 * IJROW)
                        + *(const float*)(ri + 4 * IJROW);

        hs0 += An0 - ring[0][0];
        hs1 += An1 - ring[1][0];
        hs2 += An2 - ring[2][0];
        hs3 += An3 - ring[3][0];
        hs4 += An4 - ring[4][0];
#pragma unroll
        for (int q = 0; q < 5; ++q)
#pragma unroll
            for (int i = 0; i < 4; ++i) ring[q][i] = ring[q][i + 1];
        ring[0][4] = An0; ring[1][4] = An1; ring[2][4] = An2;
        ring[3][4] = An3; ring[4][4] = An4;

        if (it >= 4) {
            const int hout = h0 + it - 4;
            if (hout < HH) {
                const float inv = 1.0f / 125.0f;
                const float uI = hs0 * inv, uJ = hs1 * inv;
                const float I2 = hs2 * inv, J2 = hs3 * inv, IJ = hs4 * inv;
                const float cross = IJ - uI * uJ;
                const float vi = I2 - uI * uI;
                const float vj = J2 - uJ * uJ;
                acc += (cross * cross) * __builtin_amdgcn_rcpf(vi * vj + 1e-5f);
            }
        }
        // single barrier per slice: double-buffered streams make the next
        // barrier the write/read fence for this buffer
    }

    // ---- block reduction, one double atomic per block ----
#pragma unroll
    for (int off = 32; off > 0; off >>= 1) acc += __shfl_down(acc, off, 64);
    const int wid = tid >> 6, lane = tid & 63;
    if (lane == 0) wpart[wid] = acc;
    __syncthreads();
    if (tid == 0)
        atomicAdd(acc_out, (double)(wpart[0] + wpart[1] + wpart[2] + wpart[3]));
}

__global__ void lncc_finalize_kernel(const double* __restrict__ acc,
                                     float* __restrict__ out) {
    const double n = (double)BB * HH * WW * DD;
    out[0] = (float)(-acc[0] / n);
}

extern "C" void kernel_launch(void* const* d_in, const int* in_sizes, int n_in,
                              void* d_out, int out_size, void* d_ws, size_t ws_size,
                              hipStream_t stream) {
    const float* pred = (const float*)d_in[0];
    const float* targ = (const float*)d_in[1];
    float* out = (float*)d_out;
    double* acc = (double*)d_ws;

    hipMemsetAsync(d_ws, 0, sizeof(double), stream);

    dim3 grid(GX, GY, GZ);     // 12 x 12 x 10 = 1440 blocks
    dim3 block(16, 16, 1);     // 256 threads
    lncc_fused_kernel<<<grid, block, 0, stream>>>(pred, targ, acc);
    lncc_finalize_kernel<<<1, 1, 0, stream>>>(acc, out);
}